// Round 13
// baseline (181.273 us; speedup 1.0000x reference)
//
#include <hip/hip_runtime.h>

#define LL 50
#define TT 1024
#define BB 256
#define START_I 47
#define END_I 48
#define NS 48        // live states (rows/cols 48,49 provably inert)
#define CT 48        // chunk length in steps
#define NCH 21       // chunks k=0..20 cover steps 1+48k .. 48+48k (<=1008)
#define MSTRIDE 2304 // 48*48 floats per chunk matrix

typedef __attribute__((ext_vector_type(8))) short bh8;
typedef __attribute__((ext_vector_type(16))) float fx16;
typedef __attribute__((ext_vector_type(4))) unsigned int ux4;

__device__ __forceinline__ unsigned int cvtpk_bf16(float lo, float hi) {
  unsigned int r;
  asm("v_cvt_pk_bf16_f32 %0, %1, %2" : "=v"(r) : "v"(lo), "v"(hi));
  return r;
}
__device__ __forceinline__ void pls(unsigned int& a, unsigned int& b) {
  asm("v_permlane32_swap_b32 %0, %1" : "+v"(a), "+v"(b));
}
__device__ __forceinline__ float rdlane(float v, int i) {
  return __int_as_float(__builtin_amdgcn_readlane(__float_as_int(v), i));
}
#define MFMA __builtin_amdgcn_mfma_f32_32x32x16_bf16

// ============================================================================
// Pass 1: per (chain b, chunk k) evolve the 48x48 transfer operator
//   M_k = prod_{t=1+48k}^{48+48k} diag(exp(emit_t)) E^T   (bf16 MFMA, f32 acc)
// STRUCTURE IS R11-VERBATIM (passed, absmax 4096): 2-step loop body, check
// every 2nd step. Only changes: wave-max via ballot (predicate-identical to
// the shfl tree: any(lane_max>=thr) == wave_max>=thr), CT 64->48 (constants
// only), waves_per_eu(4) occupancy hint.
// Output: Mb[b][k][in*48 + out] (f32), scale count Mc[b][k] (units of 2^32).
// ============================================================================
__global__ __launch_bounds__(64) __attribute__((amdgpu_waves_per_eu(4)))
void crf_pass1(const float* __restrict__ lstm, const float* __restrict__ trans,
               float* __restrict__ Mb, int* __restrict__ Mc) {
  const int bk = blockIdx.x;
  const int b = bk / NCH;
  const int k = bk - b * NCH;
  const int lane = threadIdx.x;
  const int h = lane >> 5;
  const int c31 = lane & 31;

  // ---- A fragments (R6-verified): afr[T][kc], k-idx = 16kc+8h+d, out = 32T+c31
  bh8 afr[2][3];
#pragma unroll
  for (int T = 0; T < 2; ++T)
#pragma unroll
    for (int c = 0; c < 3; ++c) {
      float ev[8];
#pragma unroll
      for (int d = 0; d < 8; ++d) {
        int si = 16 * c + 8 * h + d, so = 32 * T + c31;  // si <= 47
        ev[d] = (so < LL) ? __expf(trans[si * LL + so]) : 0.f;
      }
      ux4 dw = {cvtpk_bf16(ev[0], ev[1]), cvtpk_bf16(ev[2], ev[3]),
                cvtpk_bf16(ev[4], ev[5]), cvtpk_bf16(ev[6], ev[7])};
      afr[T][c] = __builtin_bit_cast(bh8, dw);
    }

  // ---- f row indices: D-rows owned by this lane (16 of m-tile0, 8 of m-tile1)
  int ro[24];
#pragma unroll
  for (int r = 0; r < 16; ++r) ro[r] = (r & 3) + 8 * (r >> 2) + 4 * h;
#pragma unroll
  for (int r = 0; r < 8; ++r) ro[16 + r] = 32 + (r & 3) + 8 * (r >> 2) + 4 * h;

  // ---- identity seeds for B fragments (both n-tiles) ----
  bh8 bq0[3], bq1[3];
#pragma unroll
  for (int kc = 0; kc < 3; ++kc) {
    ux4 w0v, w1v;
#pragma unroll
    for (int wd = 0; wd < 4; ++wd) {
      int lo = 16 * kc + 8 * h + 2 * wd, hi2 = lo + 1;
      int col0 = c31, col1 = 32 + c31;
      w0v[wd] = (lo == col0 ? 0x3F80u : 0u) | (hi2 == col0 ? 0x3F800000u : 0u);
      w1v[wd] = (lo == col1 ? 0x3F80u : 0u) | (hi2 == col1 ? 0x3F800000u : 0u);
    }
    bq0[kc] = __builtin_bit_cast(bh8, w0v);
    bq1[kc] = __builtin_bit_cast(bh8, w1v);
  }

  const float* __restrict__ fb = lstm + ((size_t)b * TT + (1 + k * CT)) * LL;
  float fvA[24], fvB[24];
#pragma unroll
  for (int i = 0; i < 24; ++i) fvA[i] = fb[ro[i]];

  int cnt = 0;  // scale count in units of 2^32
  float d00[16], d01[16], d10[8], d11[8];
  fx16 z16 = {};

  auto STEP = [&](const float (&fv)[24], float (&fn)[24], const float* nrow,
                  bool check) {
    fx16 a00, a01, a10, a11;
    a00 = MFMA(afr[0][0], bq0[0], z16, 0, 0, 0);
    a10 = MFMA(afr[1][0], bq0[0], z16, 0, 0, 0);
    a01 = MFMA(afr[0][0], bq1[0], z16, 0, 0, 0);
    a11 = MFMA(afr[1][0], bq1[0], z16, 0, 0, 0);
    a00 = MFMA(afr[0][1], bq0[1], a00, 0, 0, 0);
    a10 = MFMA(afr[1][1], bq0[1], a10, 0, 0, 0);
    a01 = MFMA(afr[0][1], bq1[1], a01, 0, 0, 0);
    a11 = MFMA(afr[1][1], bq1[1], a11, 0, 0, 0);
    a00 = MFMA(afr[0][2], bq0[2], a00, 0, 0, 0);
    a10 = MFMA(afr[1][2], bq0[2], a10, 0, 0, 0);
    a01 = MFMA(afr[0][2], bq1[2], a01, 0, 0, 0);
    a11 = MFMA(afr[1][2], bq1[2], a11, 0, 0, 0);
    // prefetch next step's emits while MFMAs are in flight
#pragma unroll
    for (int i = 0; i < 24; ++i) fn[i] = nrow[ro[i]];
    // multiply rows by f = exp(emit)
#pragma unroll
    for (int r = 0; r < 16; ++r) {
      float ff = __expf(fv[r]);
      d00[r] = a00[r] * ff;
      d01[r] = a01[r] * ff;
    }
#pragma unroll
    for (int r = 0; r < 8; ++r) {
      float ff = __expf(fv[16 + r]);
      d10[r] = a10[r] * ff;
      d11[r] = a11[r] * ff;
    }
    if (check) {  // ballot wave-uniform rescale; predicate == wave-max compare
      float mx = d00[0];
#pragma unroll
      for (int r = 1; r < 16; ++r) mx = fmaxf(mx, d00[r]);
#pragma unroll
      for (int r = 0; r < 16; ++r) mx = fmaxf(mx, d01[r]);
#pragma unroll
      for (int r = 0; r < 8; ++r) mx = fmaxf(mx, fmaxf(d10[r], d11[r]));
      unsigned long long up = __ballot(mx >= 0x1p32f);
      unsigned long long dn = __ballot(mx >= 0x1p-16f);
      if (up) {
#pragma unroll
        for (int r = 0; r < 16; ++r) {
          d00[r] *= 0x1p-64f;
          d01[r] *= 0x1p-64f;
        }
#pragma unroll
        for (int r = 0; r < 8; ++r) {
          d10[r] *= 0x1p-64f;
          d11[r] *= 0x1p-64f;
        }
        cnt += 2;
      } else if (!dn) {
#pragma unroll
        for (int r = 0; r < 16; ++r) {
          d00[r] *= 0x1p32f;
          d01[r] *= 0x1p32f;
        }
#pragma unroll
        for (int r = 0; r < 8; ++r) {
          d10[r] *= 0x1p32f;
          d11[r] *= 0x1p32f;
        }
        cnt -= 1;
      }
    }
    // pack D -> next B (R6-verified cvtpk+permlane), per n-tile
    auto PACK = [&](float (&p0)[16], float (&p1)[8], bh8 (&bqo)[3]) {
      unsigned P0[8], P1[4];
#pragma unroll
      for (int p_ = 0; p_ < 8; ++p_) P0[p_] = cvtpk_bf16(p0[2 * p_], p0[2 * p_ + 1]);
#pragma unroll
      for (int p_ = 0; p_ < 4; ++p_) P1[p_] = cvtpk_bf16(p1[2 * p_], p1[2 * p_ + 1]);
      pls(P0[0], P0[2]);
      pls(P0[1], P0[3]);
      pls(P0[4], P0[6]);
      pls(P0[5], P0[7]);
      pls(P1[0], P1[2]);
      pls(P1[1], P1[3]);
      ux4 w0 = {P0[0], P0[1], P0[2], P0[3]};
      ux4 w1 = {P0[4], P0[5], P0[6], P0[7]};
      ux4 w2 = {P1[0], P1[1], P1[2], P1[3]};
      bqo[0] = __builtin_bit_cast(bh8, w0);
      bqo[1] = __builtin_bit_cast(bh8, w1);
      bqo[2] = __builtin_bit_cast(bh8, w2);
    };
    PACK(d00, d10, bq0);
    PACK(d01, d11, bq1);
  };

  for (int uu = 0; uu < CT; uu += 2) {  // R11-verbatim 2-step body
    STEP(fvA, fvB, fb + (size_t)(uu + 1) * LL, false);
    STEP(fvB, fvA, fb + (size_t)(uu + 2) * LL, true);  // row <=1009: in-bounds
  }

  // ---- epilogue: LDS transpose (lt[out][in]) -> coalesced store [in][out] ----
  __shared__ float lt[NS][NS + 1];
#pragma unroll
  for (int r = 0; r < 16; ++r) lt[ro[r]][c31] = d00[r];
#pragma unroll
  for (int r = 0; r < 8; ++r) lt[ro[16 + r]][c31] = d10[r];
  if (c31 < 16) {
#pragma unroll
    for (int r = 0; r < 16; ++r) lt[ro[r]][32 + c31] = d01[r];
#pragma unroll
    for (int r = 0; r < 8; ++r) lt[ro[16 + r]][32 + c31] = d11[r];
  }
  __syncthreads();
  float* __restrict__ mg = Mb + ((size_t)b * NCH + k) * MSTRIDE;
  if (lane < NS) {
#pragma unroll
    for (int s = 0; s < NS; ++s) mg[s * NS + lane] = lt[lane][s];
  }
  if (lane == 0) Mc[b * NCH + k] = cnt;
}

// ============================================================================
// Pass 2: per chain, apply K full-chunk matrices (f32 readlane matvec), then
// <=47 remainder steps with the R3-bit-equal f32 step, then Z + labeled path.
// ============================================================================
__global__ __launch_bounds__(64) __attribute__((amdgpu_waves_per_eu(1, 1)))
void crf_pass2(const float* __restrict__ lstm, const float* __restrict__ trans,
               const int* __restrict__ lens, const int* __restrict__ tags,
               const float* __restrict__ Mb, const int* __restrict__ Mc,
               float* __restrict__ wsf) {
  const int b = blockIdx.x;
  const int lane = threadIdx.x;
  const bool act = lane < NS;
  const int cl = act ? lane : (NS - 1);
  const int len = lens[b];
  const int L = len - 1;
  const int K = L / CT;
  const int r = L - K * CT;

  // E columns f32 (48 live states; cols 48/49 provably inert)
  float e[NS];
#pragma unroll
  for (int i = 0; i < NS; ++i) {
    float ev = __expf(trans[i * LL + cl]);
    e[i] = act ? ev : 0.0f;
  }

  const float* __restrict__ base = lstm + (size_t)b * TT * LL;
  float alpha = act ? __expf(trans[START_I * LL + lane] + base[cl]) : 0.0f;
  int cnt32 = 0;  // units of 2^32

  // ---- chunk applies ----
  const float* __restrict__ mgb = Mb + (size_t)b * NCH * MSTRIDE;
  float mcur[NS], mnxt[NS];
  if (K > 0) {
#pragma unroll
    for (int i = 0; i < NS; ++i) mcur[i] = mgb[i * NS + cl];
  }
  for (int k = 0; k < K; ++k) {
    if (k + 1 < K) {
      const float* mgp = mgb + (size_t)(k + 1) * MSTRIDE;
#pragma unroll
      for (int i = 0; i < NS; ++i) mnxt[i] = mgp[i * NS + cl];
    }
    float a0 = 0.f, a1 = 0.f, a2 = 0.f, a3 = 0.f;
#pragma unroll
    for (int i = 0; i < NS; i += 4) {
      a0 = fmaf(rdlane(alpha, i + 0), mcur[i + 0], a0);
      a1 = fmaf(rdlane(alpha, i + 1), mcur[i + 1], a1);
      a2 = fmaf(rdlane(alpha, i + 2), mcur[i + 2], a2);
      a3 = fmaf(rdlane(alpha, i + 3), mcur[i + 3], a3);
    }
    float an = (a0 + a1) + (a2 + a3);
    unsigned long long up = __ballot(an >= 0x1p64f);
    unsigned long long dn = __ballot(an >= 0x1p-64f);
    float s = up ? 0x1p-64f : (dn ? 1.0f : 0x1p64f);
    cnt32 += up ? 2 : (dn ? 0 : -2);
    alpha = an * s;
    cnt32 += Mc[b * NCH + k];
    if (k + 1 < K) {
#pragma unroll
      for (int i = 0; i < NS; ++i) mcur[i] = mnxt[i];
    }
  }

  // ---- remainder steps t = CT*K+1 .. CT*K+r (R3-bit-equal f32 step) ----
  auto VSTEP = [&](float em) {
    float f = __expf(em);
    float a0 = 0.f, a1 = 0.f, a2 = 0.f, a3 = 0.f;
#pragma unroll
    for (int i = 0; i < NS; i += 4) {
      a0 = fmaf(rdlane(alpha, i + 0), e[i + 0], a0);
      a1 = fmaf(rdlane(alpha, i + 1), e[i + 1], a1);
      a2 = fmaf(rdlane(alpha, i + 2), e[i + 2], a2);
      a3 = fmaf(rdlane(alpha, i + 3), e[i + 3], a3);
    }
    float qn = ((a0 + a1) + (a2 + a3)) * f;
    unsigned long long up = __ballot(qn >= 0x1p64f);
    unsigned long long dn = __ballot(qn >= 0x1p-64f);
    float s = up ? 0x1p-64f : (dn ? 1.0f : 0x1p64f);
    cnt32 += up ? 2 : (dn ? 0 : -2);
    alpha = qn * s;
  };

  {
    const float* p = base + (size_t)(CT * K + 1) * LL + cl;  // rows <=1016 valid
    float ebuf[8];
#pragma unroll
    for (int kk = 0; kk < 8; ++kk) ebuf[kk] = p[(size_t)kk * LL];
    int u = 0;
    for (; u + 8 <= r; u += 8) {
#pragma unroll
      for (int s8 = 0; s8 < 8; ++s8) {
        VSTEP(ebuf[s8]);
        int tn = u + s8 + 8;
        tn = (tn < r) ? tn : 0;  // clamp: unused slots read a valid row
        ebuf[s8] = p[(size_t)tn * LL];
      }
    }
    if (u + 0 < r) VSTEP(ebuf[0]);
    if (u + 1 < r) VSTEP(ebuf[1]);
    if (u + 2 < r) VSTEP(ebuf[2]);
    if (u + 3 < r) VSTEP(ebuf[3]);
    if (u + 4 < r) VSTEP(ebuf[4]);
    if (u + 5 < r) VSTEP(ebuf[5]);
    if (u + 6 < r) VSTEP(ebuf[6]);
  }

  // ---- unlabeled = 32*ln2*cnt32 + ln( sum_j alpha_j * exp(trans[j][END]) )
  float w = 0.0f;
  if (act) w = alpha * __expf(trans[lane * LL + END_I]);
#pragma unroll
  for (int off = 32; off > 0; off >>= 1) w += __shfl_xor(w, off, 64);
  float unl = (float)cnt32 * 22.180709777918249f + __logf(w);

  // ---- labeled path (R3 verbatim) ----
  const int* tg = tags + (size_t)b * TT;
  float lab = 0.0f;
  for (int t0 = 0; t0 < len; t0 += 64) {
    int t = t0 + lane;
    if (t >= 1 && t < len) {
      int tp = tg[t - 1];
      int tc = tg[t];
      lab += trans[tp * LL + tc] + lstm[((size_t)b * TT + t) * LL + tc];
    }
  }
#pragma unroll
  for (int off = 32; off > 0; off >>= 1) lab += __shfl_xor(lab, off, 64);

  if (lane == 0) {
    int tg0 = tg[0];
    float begin = trans[START_I * LL + tg0] + lstm[(size_t)b * TT * LL + tg0];
    int tgl = tg[len - 1];
    float endv = trans[tgl * LL + END_I];
    wsf[b] = unl;
    wsf[BB + b] = lab + begin + endv;
  }
}

// ============================================================================
// Legacy fallback: round-3 kernel (proven, absmax 0), if ws too small.
// ============================================================================
__global__ __launch_bounds__(64) __attribute__((amdgpu_waves_per_eu(1, 1)))
void crf_fwd_legacy(
    const float* __restrict__ lstm, const float* __restrict__ trans,
    const int* __restrict__ lens, const int* __restrict__ tags,
    float* __restrict__ ws) {
  const int b = blockIdx.x;
  const int lane = threadIdx.x;
  const bool act = lane < LL;
  const int cl = act ? lane : (LL - 1);
  const int len = lens[b];

  float e[LL];
#pragma unroll
  for (int i = 0; i < LL; ++i) {
    float ev = __expf(trans[i * LL + cl]);
    e[i] = act ? ev : 0.0f;
  }
  const float* __restrict__ base = lstm + (size_t)b * TT * LL + cl;
  float q = act ? __expf(trans[START_I * LL + lane] + base[0]) : 0.0f;
  int cnt = 0;
  float s_pend = 1.0f;

  auto STEP = [&](float em) {
    float f = __expf(em) * s_pend;
    float acc0 = 0.f, acc1 = 0.f, acc2 = 0.f, acc3 = 0.f;
#pragma unroll
    for (int i = 0; i < 48; i += 4) {
      acc0 = fmaf(rdlane(q, i + 0), e[i + 0], acc0);
      acc1 = fmaf(rdlane(q, i + 1), e[i + 1], acc1);
      acc2 = fmaf(rdlane(q, i + 2), e[i + 2], acc2);
      acc3 = fmaf(rdlane(q, i + 3), e[i + 3], acc3);
    }
    acc0 = fmaf(rdlane(q, 48), e[48], acc0);
    acc1 = fmaf(rdlane(q, 49), e[49], acc1);
    float qn = ((acc0 + acc1) + (acc2 + acc3)) * f;
    unsigned long long up = __ballot(qn >= 0x1p64f);
    unsigned long long dn = __ballot(qn >= 0x1p-64f);
    s_pend = up ? 0x1p-64f : (dn ? 1.0f : 0x1p64f);
    cnt += up ? 1 : (dn ? 0 : -1);
    q = qn;
  };

  float ebuf[8];
  const float* p = base + LL;
#pragma unroll
  for (int k = 0; k < 8; ++k) ebuf[k] = p[k * LL];
  const int nb = (len - 1) >> 3;
  const int rem = (len - 1) & 7;
  for (int blk = 0; blk < nb; ++blk) {
    const float* pf = p + 8 * LL;
    if (blk < 126) {
#pragma unroll
      for (int u = 0; u < 8; ++u) {
        STEP(ebuf[u]);
        ebuf[u] = pf[u * LL];
      }
    } else {
#pragma unroll
      for (int u = 0; u < 8; ++u) {
        STEP(ebuf[u]);
        int tn = 9 + 8 * blk + u;
        if (tn < TT) ebuf[u] = pf[u * LL];
      }
    }
    p = pf;
  }
  for (int u = 0; u < rem; ++u) STEP(ebuf[u]);
  q *= s_pend;

  float wv = 0.0f;
  if (act) wv = q * __expf(trans[lane * LL + END_I]);
#pragma unroll
  for (int off = 32; off > 0; off >>= 1) wv += __shfl_xor(wv, off, 64);
  float unl = (float)cnt * 44.361419555836498f + __logf(wv);

  const int* tg = tags + (size_t)b * TT;
  float lab = 0.0f;
  for (int t0 = 0; t0 < len; t0 += 64) {
    int t = t0 + lane;
    if (t >= 1 && t < len) {
      int tp = tg[t - 1];
      int tc = tg[t];
      lab += trans[tp * LL + tc] + lstm[((size_t)b * TT + t) * LL + tc];
    }
  }
#pragma unroll
  for (int off = 32; off > 0; off >>= 1) lab += __shfl_xor(lab, off, 64);

  if (lane == 0) {
    int tg0 = tg[0];
    float begin = trans[START_I * LL + tg0] + lstm[(size_t)b * TT * LL + tg0];
    int tgl = tg[len - 1];
    float endv = trans[tgl * LL + END_I];
    ws[b] = unl;
    ws[BB + b] = lab + begin + endv;
  }
}

// Deterministic final reduce: ws[0..255] -> out[0], ws[256..511] -> out[1]
__global__ __launch_bounds__(256) void crf_reduce(const float* __restrict__ ws,
                                                  float* __restrict__ out) {
  __shared__ float sm[8];
  int tid = threadIdx.x;
  float u = ws[tid];
  float l = ws[BB + tid];
#pragma unroll
  for (int off = 32; off > 0; off >>= 1) {
    u += __shfl_xor(u, off, 64);
    l += __shfl_xor(l, off, 64);
  }
  int wid = tid >> 6;
  if ((tid & 63) == 0) {
    sm[wid] = u;
    sm[4 + wid] = l;
  }
  __syncthreads();
  if (tid == 0) {
    out[0] = (sm[0] + sm[1]) + (sm[2] + sm[3]);
    out[1] = (sm[4] + sm[5]) + (sm[6] + sm[7]);
  }
}

extern "C" void kernel_launch(void* const* d_in, const int* in_sizes, int n_in,
                              void* d_out, int out_size, void* d_ws, size_t ws_size,
                              hipStream_t stream) {
  const float* lstm = (const float*)d_in[0];
  const float* trans = (const float*)d_in[1];
  const int* lens = (const int*)d_in[2];
  const int* tags = (const int*)d_in[3];
  float* out = (float*)d_out;

  size_t need = (size_t)BB * NCH * MSTRIDE * 4 + (size_t)BB * NCH * 4 +
                (size_t)BB * 2 * 4;
  if (ws_size >= need) {
    float* Mb = (float*)d_ws;
    int* Mc = (int*)(Mb + (size_t)BB * NCH * MSTRIDE);
    float* wsf = (float*)(Mc + BB * NCH);
    crf_pass1<<<dim3(BB * NCH), dim3(64), 0, stream>>>(lstm, trans, Mb, Mc);
    crf_pass2<<<dim3(BB), dim3(64), 0, stream>>>(lstm, trans, lens, tags, Mb, Mc,
                                                 wsf);
    crf_reduce<<<dim3(1), dim3(256), 0, stream>>>(wsf, out);
  } else {
    float* wsf = (float*)d_ws;
    crf_fwd_legacy<<<dim3(BB), dim3(64), 0, stream>>>(lstm, trans, lens, tags, wsf);
    crf_reduce<<<dim3(1), dim3(256), 0, stream>>>(wsf, out);
  }
}

// Round 14
// 154.793 us; speedup vs baseline: 1.1711x; 1.1711x over previous
//
#include <hip/hip_runtime.h>

#define LL 50
#define TT 1024
#define BB 256
#define START_I 47
#define END_I 48
#define NS 48        // live states (rows/cols 48,49 provably inert)
#define CT 64        // chunk length in steps (R11-proven geometry)
#define NCH 15       // chunks k=0..14 cover steps 1+64k .. 64+64k (<=960)
#define MSTRIDE 2304 // 48*48 floats per chunk matrix

typedef __attribute__((ext_vector_type(8))) short bh8;
typedef __attribute__((ext_vector_type(16))) float fx16;
typedef __attribute__((ext_vector_type(4))) unsigned int ux4;

__device__ __forceinline__ unsigned int cvtpk_bf16(float lo, float hi) {
  unsigned int r;
  asm("v_cvt_pk_bf16_f32 %0, %1, %2" : "=v"(r) : "v"(lo), "v"(hi));
  return r;
}
__device__ __forceinline__ void pls(unsigned int& a, unsigned int& b) {
  asm("v_permlane32_swap_b32 %0, %1" : "+v"(a), "+v"(b));
}
__device__ __forceinline__ float rdlane(float v, int i) {
  return __int_as_float(__builtin_amdgcn_readlane(__float_as_int(v), i));
}
// bf16 (packed pair) -> f32, exact
__device__ __forceinline__ float blo(unsigned u) { return __uint_as_float(u << 16); }
__device__ __forceinline__ float bhi(unsigned u) { return __uint_as_float(u & 0xFFFF0000u); }
#define MFMA __builtin_amdgcn_mfma_f32_32x32x16_bf16

// ============================================================================
// Prepass: fexp[bt*24 + s2] = bf16pair( exp(lstm[bt][2*s2]), exp(lstm[bt][2*s2+1]) )
// for states 0..47 (48/49 never needed). Massively parallel, memory-bound.
// Removes ALL transcendentals + scattered f-loads from pass1's serial steps.
// ============================================================================
__global__ __launch_bounds__(256) void crf_prep_exp(
    const float* __restrict__ lstm, unsigned* __restrict__ fexp) {
  int flat = blockIdx.x * 256 + threadIdx.x;  // 0 .. 256*1024*24-1
  int bt = flat / 24;
  int s2 = flat - bt * 24;
  const float* row = lstm + (size_t)bt * LL + 2 * s2;
  fexp[flat] = cvtpk_bf16(__expf(row[0]), __expf(row[1]));
}

// ============================================================================
// Pass 1: per (chain b, chunk k) evolve the 48x48 transfer operator
//   M_k = prod_{t=1+64k}^{64+64k} diag(f_t) E^T,  f_t = bf16(exp(emit_t))
// R13-verbatim structure (2-step body, ballot rescale every 2nd step — the
// R12 NaN was cadence-4; cadence 2 is the stability boundary, frozen).
// f comes from fexp: 6 dwordx2 loads + 24 shift/mask unpacks per step
// (replaces 24 expf + 24 muls + 24 scattered loads).
// Output: Mb[b][k][in*48 + out] (f32), scale count Mc[b][k] (units of 2^32).
// ============================================================================
__global__ __launch_bounds__(64) __attribute__((amdgpu_waves_per_eu(4)))
void crf_pass1(const unsigned* __restrict__ fexp, const float* __restrict__ trans,
               float* __restrict__ Mb, int* __restrict__ Mc) {
  const int bk = blockIdx.x;
  const int b = bk / NCH;
  const int k = bk - b * NCH;
  const int lane = threadIdx.x;
  const int h = lane >> 5;
  const int c31 = lane & 31;

  // ---- A fragments (R6-verified): afr[T][kc], k-idx = 16kc+8h+d, out = 32T+c31
  bh8 afr[2][3];
#pragma unroll
  for (int T = 0; T < 2; ++T)
#pragma unroll
    for (int c = 0; c < 3; ++c) {
      float ev[8];
#pragma unroll
      for (int d = 0; d < 8; ++d) {
        int si = 16 * c + 8 * h + d, so = 32 * T + c31;  // si <= 47
        ev[d] = (so < LL) ? __expf(trans[si * LL + so]) : 0.f;
      }
      ux4 dw = {cvtpk_bf16(ev[0], ev[1]), cvtpk_bf16(ev[2], ev[3]),
                cvtpk_bf16(ev[4], ev[5]), cvtpk_bf16(ev[6], ev[7])};
      afr[T][c] = __builtin_bit_cast(bh8, dw);
    }

  // ---- D-rows owned by this lane (for the epilogue transpose) ----
  int ro[24];
#pragma unroll
  for (int r = 0; r < 16; ++r) ro[r] = (r & 3) + 8 * (r >> 2) + 4 * h;
#pragma unroll
  for (int r = 0; r < 8; ++r) ro[16 + r] = 32 + (r & 3) + 8 * (r >> 2) + 4 * h;

  // ---- identity seeds for B fragments (both n-tiles) ----
  bh8 bq0[3], bq1[3];
#pragma unroll
  for (int kc = 0; kc < 3; ++kc) {
    ux4 w0v, w1v;
#pragma unroll
    for (int wd = 0; wd < 4; ++wd) {
      int lo = 16 * kc + 8 * h + 2 * wd, hi2 = lo + 1;
      int col0 = c31, col1 = 32 + c31;
      w0v[wd] = (lo == col0 ? 0x3F80u : 0u) | (hi2 == col0 ? 0x3F800000u : 0u);
      w1v[wd] = (lo == col1 ? 0x3F80u : 0u) | (hi2 == col1 ? 0x3F800000u : 0u);
    }
    bq0[kc] = __builtin_bit_cast(bh8, w0v);
    bq1[kc] = __builtin_bit_cast(bh8, w1v);
  }

  // ---- f access: per step, rows {8q+4h..+3} (q<4) and {32+8(q-4)+4h..+3} ----
  // fexp uint2 index = bt*12 + qoff[q]; 4 consecutive bf16 per load.
  const uint2* __restrict__ fp = (const uint2*)fexp;
  int qoff[6];
#pragma unroll
  for (int q = 0; q < 4; ++q) qoff[q] = 2 * q + h;
#pragma unroll
  for (int q = 4; q < 6; ++q) qoff[q] = 8 + 2 * (q - 4) + h;

  const size_t bt0 = (size_t)b * TT + 1 + k * CT;
  uint2 fuA[6], fuB[6];
#pragma unroll
  for (int q = 0; q < 6; ++q) fuA[q] = fp[bt0 * 12 + qoff[q]];

  int cnt = 0;  // scale count in units of 2^32
  float d00[16], d01[16], d10[8], d11[8];
  fx16 z16 = {};

  auto STEP = [&](const uint2 (&fu)[6], uint2 (&fn)[6], size_t btn, bool check) {
    fx16 a00, a01, a10, a11;
    a00 = MFMA(afr[0][0], bq0[0], z16, 0, 0, 0);
    a10 = MFMA(afr[1][0], bq0[0], z16, 0, 0, 0);
    a01 = MFMA(afr[0][0], bq1[0], z16, 0, 0, 0);
    a11 = MFMA(afr[1][0], bq1[0], z16, 0, 0, 0);
    a00 = MFMA(afr[0][1], bq0[1], a00, 0, 0, 0);
    a10 = MFMA(afr[1][1], bq0[1], a10, 0, 0, 0);
    a01 = MFMA(afr[0][1], bq1[1], a01, 0, 0, 0);
    a11 = MFMA(afr[1][1], bq1[1], a11, 0, 0, 0);
    a00 = MFMA(afr[0][2], bq0[2], a00, 0, 0, 0);
    a10 = MFMA(afr[1][2], bq0[2], a10, 0, 0, 0);
    a01 = MFMA(afr[0][2], bq1[2], a01, 0, 0, 0);
    a11 = MFMA(afr[1][2], bq1[2], a11, 0, 0, 0);
    // prefetch next step's f while MFMAs are in flight
#pragma unroll
    for (int q = 0; q < 6; ++q) fn[q] = fp[btn * 12 + qoff[q]];
    // unpack bf16 f -> f32 (exact) ; ff index == r / 16+r by construction
    float ff[24];
#pragma unroll
    for (int q = 0; q < 6; ++q) {
      ff[4 * q + 0] = blo(fu[q].x);
      ff[4 * q + 1] = bhi(fu[q].x);
      ff[4 * q + 2] = blo(fu[q].y);
      ff[4 * q + 3] = bhi(fu[q].y);
    }
#pragma unroll
    for (int r = 0; r < 16; ++r) {
      d00[r] = a00[r] * ff[r];
      d01[r] = a01[r] * ff[r];
    }
#pragma unroll
    for (int r = 0; r < 8; ++r) {
      d10[r] = a10[r] * ff[16 + r];
      d11[r] = a11[r] * ff[16 + r];
    }
    if (check) {  // ballot wave-uniform rescale (cadence 2 — frozen, see R12)
      float mx = d00[0];
#pragma unroll
      for (int r = 1; r < 16; ++r) mx = fmaxf(mx, d00[r]);
#pragma unroll
      for (int r = 0; r < 16; ++r) mx = fmaxf(mx, d01[r]);
#pragma unroll
      for (int r = 0; r < 8; ++r) mx = fmaxf(mx, fmaxf(d10[r], d11[r]));
      unsigned long long up = __ballot(mx >= 0x1p32f);
      unsigned long long dn = __ballot(mx >= 0x1p-16f);
      if (up) {
#pragma unroll
        for (int r = 0; r < 16; ++r) {
          d00[r] *= 0x1p-64f;
          d01[r] *= 0x1p-64f;
        }
#pragma unroll
        for (int r = 0; r < 8; ++r) {
          d10[r] *= 0x1p-64f;
          d11[r] *= 0x1p-64f;
        }
        cnt += 2;
      } else if (!dn) {
#pragma unroll
        for (int r = 0; r < 16; ++r) {
          d00[r] *= 0x1p32f;
          d01[r] *= 0x1p32f;
        }
#pragma unroll
        for (int r = 0; r < 8; ++r) {
          d10[r] *= 0x1p32f;
          d11[r] *= 0x1p32f;
        }
        cnt -= 1;
      }
    }
    // pack D -> next B (R6-verified cvtpk+permlane), per n-tile
    auto PACK = [&](float (&p0)[16], float (&p1)[8], bh8 (&bqo)[3]) {
      unsigned P0[8], P1[4];
#pragma unroll
      for (int p_ = 0; p_ < 8; ++p_) P0[p_] = cvtpk_bf16(p0[2 * p_], p0[2 * p_ + 1]);
#pragma unroll
      for (int p_ = 0; p_ < 4; ++p_) P1[p_] = cvtpk_bf16(p1[2 * p_], p1[2 * p_ + 1]);
      pls(P0[0], P0[2]);
      pls(P0[1], P0[3]);
      pls(P0[4], P0[6]);
      pls(P0[5], P0[7]);
      pls(P1[0], P1[2]);
      pls(P1[1], P1[3]);
      ux4 w0 = {P0[0], P0[1], P0[2], P0[3]};
      ux4 w1 = {P0[4], P0[5], P0[6], P0[7]};
      ux4 w2 = {P1[0], P1[1], P1[2], P1[3]};
      bqo[0] = __builtin_bit_cast(bh8, w0);
      bqo[1] = __builtin_bit_cast(bh8, w1);
      bqo[2] = __builtin_bit_cast(bh8, w2);
    };
    PACK(d00, d10, bq0);
    PACK(d01, d11, bq1);
  };

  for (int uu = 0; uu < CT; uu += 2) {  // R11/R13-verbatim 2-step body
    STEP(fuA, fuB, bt0 + uu + 1, false);
    STEP(fuB, fuA, bt0 + uu + 2, true);  // max bt = b*TT+961: in-bounds
  }

  // ---- epilogue: LDS transpose (lt[out][in]) -> store [in][out] ----
  __shared__ float lt[NS][NS + 1];
#pragma unroll
  for (int r = 0; r < 16; ++r) lt[ro[r]][c31] = d00[r];
#pragma unroll
  for (int r = 0; r < 8; ++r) lt[ro[16 + r]][c31] = d10[r];
  if (c31 < 16) {
#pragma unroll
    for (int r = 0; r < 16; ++r) lt[ro[r]][32 + c31] = d01[r];
#pragma unroll
    for (int r = 0; r < 8; ++r) lt[ro[16 + r]][32 + c31] = d11[r];
  }
  __syncthreads();
  float* __restrict__ mg = Mb + ((size_t)b * NCH + k) * MSTRIDE;
  if (lane < NS) {
#pragma unroll
    for (int s = 0; s < NS; ++s) mg[s * NS + lane] = lt[lane][s];
  }
  if (lane == 0) Mc[b * NCH + k] = cnt;
}

// ============================================================================
// Pass 2: R11-VERBATIM (passed twice). Per chain: K chunk matvecs + <=63
// remainder steps (R3-bit-equal f32) + Z + labeled path.
// ============================================================================
__global__ __launch_bounds__(64) __attribute__((amdgpu_waves_per_eu(1, 1)))
void crf_pass2(const float* __restrict__ lstm, const float* __restrict__ trans,
               const int* __restrict__ lens, const int* __restrict__ tags,
               const float* __restrict__ Mb, const int* __restrict__ Mc,
               float* __restrict__ wsf) {
  const int b = blockIdx.x;
  const int lane = threadIdx.x;
  const bool act = lane < NS;
  const int cl = act ? lane : (NS - 1);
  const int len = lens[b];
  const int L = len - 1;
  const int K = L / CT;
  const int r = L - K * CT;

  float e[NS];
#pragma unroll
  for (int i = 0; i < NS; ++i) {
    float ev = __expf(trans[i * LL + cl]);
    e[i] = act ? ev : 0.0f;
  }

  const float* __restrict__ base = lstm + (size_t)b * TT * LL;
  float alpha = act ? __expf(trans[START_I * LL + lane] + base[cl]) : 0.0f;
  int cnt32 = 0;  // units of 2^32

  const float* __restrict__ mgb = Mb + (size_t)b * NCH * MSTRIDE;
  float mcur[NS], mnxt[NS];
  if (K > 0) {
#pragma unroll
    for (int i = 0; i < NS; ++i) mcur[i] = mgb[i * NS + cl];
  }
  for (int k = 0; k < K; ++k) {
    if (k + 1 < K) {
      const float* mgp = mgb + (size_t)(k + 1) * MSTRIDE;
#pragma unroll
      for (int i = 0; i < NS; ++i) mnxt[i] = mgp[i * NS + cl];
    }
    float a0 = 0.f, a1 = 0.f, a2 = 0.f, a3 = 0.f;
#pragma unroll
    for (int i = 0; i < NS; i += 4) {
      a0 = fmaf(rdlane(alpha, i + 0), mcur[i + 0], a0);
      a1 = fmaf(rdlane(alpha, i + 1), mcur[i + 1], a1);
      a2 = fmaf(rdlane(alpha, i + 2), mcur[i + 2], a2);
      a3 = fmaf(rdlane(alpha, i + 3), mcur[i + 3], a3);
    }
    float an = (a0 + a1) + (a2 + a3);
    unsigned long long up = __ballot(an >= 0x1p64f);
    unsigned long long dn = __ballot(an >= 0x1p-64f);
    float s = up ? 0x1p-64f : (dn ? 1.0f : 0x1p64f);
    cnt32 += up ? 2 : (dn ? 0 : -2);
    alpha = an * s;
    cnt32 += Mc[b * NCH + k];
    if (k + 1 < K) {
#pragma unroll
      for (int i = 0; i < NS; ++i) mcur[i] = mnxt[i];
    }
  }

  auto VSTEP = [&](float em) {
    float f = __expf(em);
    float a0 = 0.f, a1 = 0.f, a2 = 0.f, a3 = 0.f;
#pragma unroll
    for (int i = 0; i < NS; i += 4) {
      a0 = fmaf(rdlane(alpha, i + 0), e[i + 0], a0);
      a1 = fmaf(rdlane(alpha, i + 1), e[i + 1], a1);
      a2 = fmaf(rdlane(alpha, i + 2), e[i + 2], a2);
      a3 = fmaf(rdlane(alpha, i + 3), e[i + 3], a3);
    }
    float qn = ((a0 + a1) + (a2 + a3)) * f;
    unsigned long long up = __ballot(qn >= 0x1p64f);
    unsigned long long dn = __ballot(qn >= 0x1p-64f);
    float s = up ? 0x1p-64f : (dn ? 1.0f : 0x1p64f);
    cnt32 += up ? 2 : (dn ? 0 : -2);
    alpha = qn * s;
  };

  {
    const float* p = base + (size_t)(CT * K + 1) * LL + cl;  // rows <=968 valid
    float ebuf[8];
#pragma unroll
    for (int kk = 0; kk < 8; ++kk) ebuf[kk] = p[(size_t)kk * LL];
    int u = 0;
    for (; u + 8 <= r; u += 8) {
#pragma unroll
      for (int s8 = 0; s8 < 8; ++s8) {
        VSTEP(ebuf[s8]);
        int tn = u + s8 + 8;
        tn = (tn < r) ? tn : 0;  // clamp: unused slots read a valid row
        ebuf[s8] = p[(size_t)tn * LL];
      }
    }
    if (u + 0 < r) VSTEP(ebuf[0]);
    if (u + 1 < r) VSTEP(ebuf[1]);
    if (u + 2 < r) VSTEP(ebuf[2]);
    if (u + 3 < r) VSTEP(ebuf[3]);
    if (u + 4 < r) VSTEP(ebuf[4]);
    if (u + 5 < r) VSTEP(ebuf[5]);
    if (u + 6 < r) VSTEP(ebuf[6]);
  }

  float w = 0.0f;
  if (act) w = alpha * __expf(trans[lane * LL + END_I]);
#pragma unroll
  for (int off = 32; off > 0; off >>= 1) w += __shfl_xor(w, off, 64);
  float unl = (float)cnt32 * 22.180709777918249f + __logf(w);

  const int* tg = tags + (size_t)b * TT;
  float lab = 0.0f;
  for (int t0 = 0; t0 < len; t0 += 64) {
    int t = t0 + lane;
    if (t >= 1 && t < len) {
      int tp = tg[t - 1];
      int tc = tg[t];
      lab += trans[tp * LL + tc] + lstm[((size_t)b * TT + t) * LL + tc];
    }
  }
#pragma unroll
  for (int off = 32; off > 0; off >>= 1) lab += __shfl_xor(lab, off, 64);

  if (lane == 0) {
    int tg0 = tg[0];
    float begin = trans[START_I * LL + tg0] + lstm[(size_t)b * TT * LL + tg0];
    int tgl = tg[len - 1];
    float endv = trans[tgl * LL + END_I];
    wsf[b] = unl;
    wsf[BB + b] = lab + begin + endv;
  }
}

// ============================================================================
// Legacy fallback: round-3 kernel (proven, absmax 0), if ws too small.
// ============================================================================
__global__ __launch_bounds__(64) __attribute__((amdgpu_waves_per_eu(1, 1)))
void crf_fwd_legacy(
    const float* __restrict__ lstm, const float* __restrict__ trans,
    const int* __restrict__ lens, const int* __restrict__ tags,
    float* __restrict__ ws) {
  const int b = blockIdx.x;
  const int lane = threadIdx.x;
  const bool act = lane < LL;
  const int cl = act ? lane : (LL - 1);
  const int len = lens[b];

  float e[LL];
#pragma unroll
  for (int i = 0; i < LL; ++i) {
    float ev = __expf(trans[i * LL + cl]);
    e[i] = act ? ev : 0.0f;
  }
  const float* __restrict__ base = lstm + (size_t)b * TT * LL + cl;
  float q = act ? __expf(trans[START_I * LL + lane] + base[0]) : 0.0f;
  int cnt = 0;
  float s_pend = 1.0f;

  auto STEP = [&](float em) {
    float f = __expf(em) * s_pend;
    float acc0 = 0.f, acc1 = 0.f, acc2 = 0.f, acc3 = 0.f;
#pragma unroll
    for (int i = 0; i < 48; i += 4) {
      acc0 = fmaf(rdlane(q, i + 0), e[i + 0], acc0);
      acc1 = fmaf(rdlane(q, i + 1), e[i + 1], acc1);
      acc2 = fmaf(rdlane(q, i + 2), e[i + 2], acc2);
      acc3 = fmaf(rdlane(q, i + 3), e[i + 3], acc3);
    }
    acc0 = fmaf(rdlane(q, 48), e[48], acc0);
    acc1 = fmaf(rdlane(q, 49), e[49], acc1);
    float qn = ((acc0 + acc1) + (acc2 + acc3)) * f;
    unsigned long long up = __ballot(qn >= 0x1p64f);
    unsigned long long dn = __ballot(qn >= 0x1p-64f);
    s_pend = up ? 0x1p-64f : (dn ? 1.0f : 0x1p64f);
    cnt += up ? 1 : (dn ? 0 : -1);
    q = qn;
  };

  float ebuf[8];
  const float* p = base + LL;
#pragma unroll
  for (int k = 0; k < 8; ++k) ebuf[k] = p[k * LL];
  const int nb = (len - 1) >> 3;
  const int rem = (len - 1) & 7;
  for (int blk = 0; blk < nb; ++blk) {
    const float* pf = p + 8 * LL;
    if (blk < 126) {
#pragma unroll
      for (int u = 0; u < 8; ++u) {
        STEP(ebuf[u]);
        ebuf[u] = pf[u * LL];
      }
    } else {
#pragma unroll
      for (int u = 0; u < 8; ++u) {
        STEP(ebuf[u]);
        int tn = 9 + 8 * blk + u;
        if (tn < TT) ebuf[u] = pf[u * LL];
      }
    }
    p = pf;
  }
  for (int u = 0; u < rem; ++u) STEP(ebuf[u]);
  q *= s_pend;

  float wv = 0.0f;
  if (act) wv = q * __expf(trans[lane * LL + END_I]);
#pragma unroll
  for (int off = 32; off > 0; off >>= 1) wv += __shfl_xor(wv, off, 64);
  float unl = (float)cnt * 44.361419555836498f + __logf(wv);

  const int* tg = tags + (size_t)b * TT;
  float lab = 0.0f;
  for (int t0 = 0; t0 < len; t0 += 64) {
    int t = t0 + lane;
    if (t >= 1 && t < len) {
      int tp = tg[t - 1];
      int tc = tg[t];
      lab += trans[tp * LL + tc] + lstm[((size_t)b * TT + t) * LL + tc];
    }
  }
#pragma unroll
  for (int off = 32; off > 0; off >>= 1) lab += __shfl_xor(lab, off, 64);

  if (lane == 0) {
    int tg0 = tg[0];
    float begin = trans[START_I * LL + tg0] + lstm[(size_t)b * TT * LL + tg0];
    int tgl = tg[len - 1];
    float endv = trans[tgl * LL + END_I];
    ws[b] = unl;
    ws[BB + b] = lab + begin + endv;
  }
}

// Deterministic final reduce: ws[0..255] -> out[0], ws[256..511] -> out[1]
__global__ __launch_bounds__(256) void crf_reduce(const float* __restrict__ ws,
                                                  float* __restrict__ out) {
  __shared__ float sm[8];
  int tid = threadIdx.x;
  float u = ws[tid];
  float l = ws[BB + tid];
#pragma unroll
  for (int off = 32; off > 0; off >>= 1) {
    u += __shfl_xor(u, off, 64);
    l += __shfl_xor(l, off, 64);
  }
  int wid = tid >> 6;
  if ((tid & 63) == 0) {
    sm[wid] = u;
    sm[4 + wid] = l;
  }
  __syncthreads();
  if (tid == 0) {
    out[0] = (sm[0] + sm[1]) + (sm[2] + sm[3]);
    out[1] = (sm[4] + sm[5]) + (sm[6] + sm[7]);
  }
}

extern "C" void kernel_launch(void* const* d_in, const int* in_sizes, int n_in,
                              void* d_out, int out_size, void* d_ws, size_t ws_size,
                              hipStream_t stream) {
  const float* lstm = (const float*)d_in[0];
  const float* trans = (const float*)d_in[1];
  const int* lens = (const int*)d_in[2];
  const int* tags = (const int*)d_in[3];
  float* out = (float*)d_out;

  const size_t fexpN = (size_t)BB * TT * 24;       // uints (25.2 MB)
  const size_t MbN = (size_t)BB * NCH * MSTRIDE;   // floats (35.4 MB)
  size_t need = fexpN * 4 + MbN * 4 + (size_t)BB * NCH * 4 + (size_t)BB * 2 * 4;
  if (ws_size >= need) {
    unsigned* fexp = (unsigned*)d_ws;
    float* Mb = (float*)(fexp + fexpN);
    int* Mc = (int*)(Mb + MbN);
    float* wsf = (float*)(Mc + BB * NCH);
    crf_prep_exp<<<dim3(BB * TT * 24 / 256), dim3(256), 0, stream>>>(lstm, fexp);
    crf_pass1<<<dim3(BB * NCH), dim3(64), 0, stream>>>(fexp, trans, Mb, Mc);
    crf_pass2<<<dim3(BB), dim3(64), 0, stream>>>(lstm, trans, lens, tags, Mb, Mc,
                                                 wsf);
    crf_reduce<<<dim3(1), dim3(256), 0, stream>>>(wsf, out);
  } else {
    float* wsf = (float*)d_ws;
    crf_fwd_legacy<<<dim3(BB), dim3(64), 0, stream>>>(lstm, trans, lens, tags, wsf);
    crf_reduce<<<dim3(1), dim3(256), 0, stream>>>(wsf, out);
  }
}

// Round 15
// 152.422 us; speedup vs baseline: 1.1893x; 1.0156x over previous
//
#include <hip/hip_runtime.h>

#define LL 50
#define TT 1024
#define BB 256
#define START_I 47
#define END_I 48
#define NS 48        // live states (rows/cols 48,49 provably inert)
#define CT 64        // chunk length in steps (R11-proven geometry)
#define NCH 15       // chunks k=0..14 cover steps 1+64k .. 64+64k (<=960)
#define MSTRIDE 2304 // 48*48 floats per chunk matrix

typedef __attribute__((ext_vector_type(8))) short bh8;
typedef __attribute__((ext_vector_type(16))) float fx16;
typedef __attribute__((ext_vector_type(4))) unsigned int ux4;
typedef __attribute__((ext_vector_type(2))) float fl2;  // -> v_pk_*_f32

__device__ __forceinline__ unsigned int cvtpk_bf16(float lo, float hi) {
  unsigned int r;
  asm("v_cvt_pk_bf16_f32 %0, %1, %2" : "=v"(r) : "v"(lo), "v"(hi));
  return r;
}
__device__ __forceinline__ void pls(unsigned int& a, unsigned int& b) {
  asm("v_permlane32_swap_b32 %0, %1" : "+v"(a), "+v"(b));
}
__device__ __forceinline__ float rdlane(float v, int i) {
  return __int_as_float(__builtin_amdgcn_readlane(__float_as_int(v), i));
}
// bf16 (packed pair) -> f32, exact
__device__ __forceinline__ float blo(unsigned u) { return __uint_as_float(u << 16); }
__device__ __forceinline__ float bhi(unsigned u) { return __uint_as_float(u & 0xFFFF0000u); }
// nested-triple max -> v_max3_f32 (exact; reassociation-safe)
__device__ __forceinline__ float fmax3(float a, float b, float c) {
  return fmaxf(fmaxf(a, b), c);
}
#define MFMA __builtin_amdgcn_mfma_f32_32x32x16_bf16

// ============================================================================
// Prepass: fexp[bt*24 + s2] = bf16pair( exp(lstm[bt][2*s2]), exp(lstm[bt][2*s2+1]) )
// R14-verbatim.
// ============================================================================
__global__ __launch_bounds__(256) void crf_prep_exp(
    const float* __restrict__ lstm, unsigned* __restrict__ fexp) {
  int flat = blockIdx.x * 256 + threadIdx.x;  // 0 .. 256*1024*24-1
  int bt = flat / 24;
  int s2 = flat - bt * 24;
  const float* row = lstm + (size_t)bt * LL + 2 * s2;
  fexp[flat] = cvtpk_bf16(__expf(row[0]), __expf(row[1]));
}

// ============================================================================
// Pass 1: per (chain b, chunk k) evolve the 48x48 transfer operator.
// R14 values BIT-IDENTICAL; changes are issue-count only:
//  - f-apply & rescale muls as float2 (v_pk_mul_f32; scalar fallback harmless)
//  - fmax reduction as nested triples (v_max3_f32)
//  - f loads: pointer bump +12/step + immediate offsets (no per-step idx mul)
// Cadence-2 ballot rescale FROZEN (R12: cadence 4 NaNs — decay outruns the
// single 2^32 up-scale).
// ============================================================================
__global__ __launch_bounds__(64) __attribute__((amdgpu_waves_per_eu(4)))
void crf_pass1(const unsigned* __restrict__ fexp, const float* __restrict__ trans,
               float* __restrict__ Mb, int* __restrict__ Mc) {
  const int bk = blockIdx.x;
  const int b = bk / NCH;
  const int k = bk - b * NCH;
  const int lane = threadIdx.x;
  const int h = lane >> 5;
  const int c31 = lane & 31;

  // ---- A fragments (R6-verified): afr[T][kc], k-idx = 16kc+8h+d, out = 32T+c31
  bh8 afr[2][3];
#pragma unroll
  for (int T = 0; T < 2; ++T)
#pragma unroll
    for (int c = 0; c < 3; ++c) {
      float ev[8];
#pragma unroll
      for (int d = 0; d < 8; ++d) {
        int si = 16 * c + 8 * h + d, so = 32 * T + c31;  // si <= 47
        ev[d] = (so < LL) ? __expf(trans[si * LL + so]) : 0.f;
      }
      ux4 dw = {cvtpk_bf16(ev[0], ev[1]), cvtpk_bf16(ev[2], ev[3]),
                cvtpk_bf16(ev[4], ev[5]), cvtpk_bf16(ev[6], ev[7])};
      afr[T][c] = __builtin_bit_cast(bh8, dw);
    }

  // ---- D-rows owned by this lane (for the epilogue transpose) ----
  int ro[24];
#pragma unroll
  for (int r = 0; r < 16; ++r) ro[r] = (r & 3) + 8 * (r >> 2) + 4 * h;
#pragma unroll
  for (int r = 0; r < 8; ++r) ro[16 + r] = 32 + (r & 3) + 8 * (r >> 2) + 4 * h;

  // ---- identity seeds for B fragments (both n-tiles) ----
  bh8 bq0[3], bq1[3];
#pragma unroll
  for (int kc = 0; kc < 3; ++kc) {
    ux4 w0v, w1v;
#pragma unroll
    for (int wd = 0; wd < 4; ++wd) {
      int lo = 16 * kc + 8 * h + 2 * wd, hi2 = lo + 1;
      int col0 = c31, col1 = 32 + c31;
      w0v[wd] = (lo == col0 ? 0x3F80u : 0u) | (hi2 == col0 ? 0x3F800000u : 0u);
      w1v[wd] = (lo == col1 ? 0x3F80u : 0u) | (hi2 == col1 ? 0x3F800000u : 0u);
    }
    bq0[kc] = __builtin_bit_cast(bh8, w0v);
    bq1[kc] = __builtin_bit_cast(bh8, w1v);
  }

  // ---- f pointer: uint2 granules; base includes h; step bump = +12 ----
  // uint2 j holds states {4j..4j+3}; this lane needs granules h+{0,2,4,6,8,10}.
  const uint2* __restrict__ fp = (const uint2*)fexp;
  const size_t bt0 = (size_t)b * TT + 1 + k * CT;
  const uint2* pc = fp + bt0 * 12 + h;

  uint2 fuA[6], fuB[6];
  fuA[0] = pc[0];
  fuA[1] = pc[2];
  fuA[2] = pc[4];
  fuA[3] = pc[6];
  fuA[4] = pc[8];
  fuA[5] = pc[10];

  int cnt = 0;  // scale count in units of 2^32
  fl2 d00[8], d01[8], d10[4], d11[4];
  fx16 z16 = {};

  auto STEP = [&](const uint2 (&fu)[6], uint2 (&fn)[6], const uint2* pn,
                  bool check) {
    fx16 a00, a01, a10, a11;
    a00 = MFMA(afr[0][0], bq0[0], z16, 0, 0, 0);
    a10 = MFMA(afr[1][0], bq0[0], z16, 0, 0, 0);
    a01 = MFMA(afr[0][0], bq1[0], z16, 0, 0, 0);
    a11 = MFMA(afr[1][0], bq1[0], z16, 0, 0, 0);
    a00 = MFMA(afr[0][1], bq0[1], a00, 0, 0, 0);
    a10 = MFMA(afr[1][1], bq0[1], a10, 0, 0, 0);
    a01 = MFMA(afr[0][1], bq1[1], a01, 0, 0, 0);
    a11 = MFMA(afr[1][1], bq1[1], a11, 0, 0, 0);
    a00 = MFMA(afr[0][2], bq0[2], a00, 0, 0, 0);
    a10 = MFMA(afr[1][2], bq0[2], a10, 0, 0, 0);
    a01 = MFMA(afr[0][2], bq1[2], a01, 0, 0, 0);
    a11 = MFMA(afr[1][2], bq1[2], a11, 0, 0, 0);
    // prefetch next step's f while MFMAs are in flight (imm-offset loads)
    fn[0] = pn[0];
    fn[1] = pn[2];
    fn[2] = pn[4];
    fn[3] = pn[6];
    fn[4] = pn[8];
    fn[5] = pn[10];
    // unpack bf16 f -> float2 (exact); ff2[p] pairs rows (2p, 2p+1)
    fl2 ff2[12];
#pragma unroll
    for (int q = 0; q < 6; ++q) {
      ff2[2 * q] = (fl2){blo(fu[q].x), bhi(fu[q].x)};
      ff2[2 * q + 1] = (fl2){blo(fu[q].y), bhi(fu[q].y)};
    }
    // f-apply as packed-f32 muls (bit-identical to scalar)
#pragma unroll
    for (int p = 0; p < 8; ++p) {
      fl2 v0 = {a00[2 * p], a00[2 * p + 1]};
      fl2 v1 = {a01[2 * p], a01[2 * p + 1]};
      d00[p] = v0 * ff2[p];
      d01[p] = v1 * ff2[p];
    }
#pragma unroll
    for (int p = 0; p < 4; ++p) {
      fl2 v0 = {a10[2 * p], a10[2 * p + 1]};
      fl2 v1 = {a11[2 * p], a11[2 * p + 1]};
      d10[p] = v0 * ff2[8 + p];
      d11[p] = v1 * ff2[8 + p];
    }
    if (check) {  // ballot rescale, cadence 2 (frozen); max via v_max3 triples
      float v[48];
#pragma unroll
      for (int p = 0; p < 8; ++p) {
        v[2 * p] = d00[p].x;
        v[2 * p + 1] = d00[p].y;
        v[16 + 2 * p] = d01[p].x;
        v[16 + 2 * p + 1] = d01[p].y;
      }
#pragma unroll
      for (int p = 0; p < 4; ++p) {
        v[32 + 2 * p] = d10[p].x;
        v[32 + 2 * p + 1] = d10[p].y;
        v[40 + 2 * p] = d11[p].x;
        v[40 + 2 * p + 1] = d11[p].y;
      }
      float t[16];
#pragma unroll
      for (int i = 0; i < 16; ++i)
        t[i] = fmax3(v[3 * i], v[3 * i + 1], v[3 * i + 2]);
      float u0 = fmax3(t[0], t[1], t[2]);
      float u1 = fmax3(t[3], t[4], t[5]);
      float u2 = fmax3(t[6], t[7], t[8]);
      float u3 = fmax3(t[9], t[10], t[11]);
      float u4 = fmax3(t[12], t[13], t[14]);
      float mx = fmaxf(fmax3(u0, u1, u2), fmax3(u3, u4, t[15]));
      unsigned long long up = __ballot(mx >= 0x1p32f);
      unsigned long long dn = __ballot(mx >= 0x1p-16f);
      if (up) {
        fl2 s2 = {0x1p-64f, 0x1p-64f};
#pragma unroll
        for (int p = 0; p < 8; ++p) {
          d00[p] = d00[p] * s2;
          d01[p] = d01[p] * s2;
        }
#pragma unroll
        for (int p = 0; p < 4; ++p) {
          d10[p] = d10[p] * s2;
          d11[p] = d11[p] * s2;
        }
        cnt += 2;
      } else if (!dn) {
        fl2 s2 = {0x1p32f, 0x1p32f};
#pragma unroll
        for (int p = 0; p < 8; ++p) {
          d00[p] = d00[p] * s2;
          d01[p] = d01[p] * s2;
        }
#pragma unroll
        for (int p = 0; p < 4; ++p) {
          d10[p] = d10[p] * s2;
          d11[p] = d11[p] * s2;
        }
        cnt -= 1;
      }
    }
    // pack D -> next B (R6-verified cvtpk+permlane), per n-tile
    {
      unsigned P0[8], P1[4];
#pragma unroll
      for (int p = 0; p < 8; ++p) P0[p] = cvtpk_bf16(d00[p].x, d00[p].y);
#pragma unroll
      for (int p = 0; p < 4; ++p) P1[p] = cvtpk_bf16(d10[p].x, d10[p].y);
      pls(P0[0], P0[2]);
      pls(P0[1], P0[3]);
      pls(P0[4], P0[6]);
      pls(P0[5], P0[7]);
      pls(P1[0], P1[2]);
      pls(P1[1], P1[3]);
      ux4 w0 = {P0[0], P0[1], P0[2], P0[3]};
      ux4 w1 = {P0[4], P0[5], P0[6], P0[7]};
      ux4 w2 = {P1[0], P1[1], P1[2], P1[3]};
      bq0[0] = __builtin_bit_cast(bh8, w0);
      bq0[1] = __builtin_bit_cast(bh8, w1);
      bq0[2] = __builtin_bit_cast(bh8, w2);
    }
    {
      unsigned P0[8], P1[4];
#pragma unroll
      for (int p = 0; p < 8; ++p) P0[p] = cvtpk_bf16(d01[p].x, d01[p].y);
#pragma unroll
      for (int p = 0; p < 4; ++p) P1[p] = cvtpk_bf16(d11[p].x, d11[p].y);
      pls(P0[0], P0[2]);
      pls(P0[1], P0[3]);
      pls(P0[4], P0[6]);
      pls(P0[5], P0[7]);
      pls(P1[0], P1[2]);
      pls(P1[1], P1[3]);
      ux4 w0 = {P0[0], P0[1], P0[2], P0[3]};
      ux4 w1 = {P0[4], P0[5], P0[6], P0[7]};
      ux4 w2 = {P1[0], P1[1], P1[2], P1[3]};
      bq1[0] = __builtin_bit_cast(bh8, w0);
      bq1[1] = __builtin_bit_cast(bh8, w1);
      bq1[2] = __builtin_bit_cast(bh8, w2);
    }
  };

  for (int uu = 0; uu < CT; uu += 2) {  // 2-step body, cadence-2 check
    STEP(fuA, fuB, pc + 12, false);
    STEP(fuB, fuA, pc + 24, true);  // prefetch <= step 961: in-bounds
    pc += 24;
  }

  // ---- epilogue: LDS transpose (lt[out][in]) -> store [in][out] ----
  __shared__ float lt[NS][NS + 1];
#pragma unroll
  for (int r = 0; r < 16; ++r)
    lt[ro[r]][c31] = (r & 1) ? d00[r >> 1].y : d00[r >> 1].x;
#pragma unroll
  for (int r = 0; r < 8; ++r)
    lt[ro[16 + r]][c31] = (r & 1) ? d10[r >> 1].y : d10[r >> 1].x;
  if (c31 < 16) {
#pragma unroll
    for (int r = 0; r < 16; ++r)
      lt[ro[r]][32 + c31] = (r & 1) ? d01[r >> 1].y : d01[r >> 1].x;
#pragma unroll
    for (int r = 0; r < 8; ++r)
      lt[ro[16 + r]][32 + c31] = (r & 1) ? d11[r >> 1].y : d11[r >> 1].x;
  }
  __syncthreads();
  float* __restrict__ mg = Mb + ((size_t)b * NCH + k) * MSTRIDE;
  if (lane < NS) {
#pragma unroll
    for (int s = 0; s < NS; ++s) mg[s * NS + lane] = lt[lane][s];
  }
  if (lane == 0) Mc[b * NCH + k] = cnt;
}

// ============================================================================
// Pass 2: R11/R14-VERBATIM. Per chain: K chunk matvecs + <=63 remainder steps
// (R3-bit-equal f32) + Z + labeled path.
// ============================================================================
__global__ __launch_bounds__(64) __attribute__((amdgpu_waves_per_eu(1, 1)))
void crf_pass2(const float* __restrict__ lstm, const float* __restrict__ trans,
               const int* __restrict__ lens, const int* __restrict__ tags,
               const float* __restrict__ Mb, const int* __restrict__ Mc,
               float* __restrict__ wsf) {
  const int b = blockIdx.x;
  const int lane = threadIdx.x;
  const bool act = lane < NS;
  const int cl = act ? lane : (NS - 1);
  const int len = lens[b];
  const int L = len - 1;
  const int K = L / CT;
  const int r = L - K * CT;

  float e[NS];
#pragma unroll
  for (int i = 0; i < NS; ++i) {
    float ev = __expf(trans[i * LL + cl]);
    e[i] = act ? ev : 0.0f;
  }

  const float* __restrict__ base = lstm + (size_t)b * TT * LL;
  float alpha = act ? __expf(trans[START_I * LL + lane] + base[cl]) : 0.0f;
  int cnt32 = 0;  // units of 2^32

  const float* __restrict__ mgb = Mb + (size_t)b * NCH * MSTRIDE;
  float mcur[NS], mnxt[NS];
  if (K > 0) {
#pragma unroll
    for (int i = 0; i < NS; ++i) mcur[i] = mgb[i * NS + cl];
  }
  for (int k = 0; k < K; ++k) {
    if (k + 1 < K) {
      const float* mgp = mgb + (size_t)(k + 1) * MSTRIDE;
#pragma unroll
      for (int i = 0; i < NS; ++i) mnxt[i] = mgp[i * NS + cl];
    }
    float a0 = 0.f, a1 = 0.f, a2 = 0.f, a3 = 0.f;
#pragma unroll
    for (int i = 0; i < NS; i += 4) {
      a0 = fmaf(rdlane(alpha, i + 0), mcur[i + 0], a0);
      a1 = fmaf(rdlane(alpha, i + 1), mcur[i + 1], a1);
      a2 = fmaf(rdlane(alpha, i + 2), mcur[i + 2], a2);
      a3 = fmaf(rdlane(alpha, i + 3), mcur[i + 3], a3);
    }
    float an = (a0 + a1) + (a2 + a3);
    unsigned long long up = __ballot(an >= 0x1p64f);
    unsigned long long dn = __ballot(an >= 0x1p-64f);
    float s = up ? 0x1p-64f : (dn ? 1.0f : 0x1p64f);
    cnt32 += up ? 2 : (dn ? 0 : -2);
    alpha = an * s;
    cnt32 += Mc[b * NCH + k];
    if (k + 1 < K) {
#pragma unroll
      for (int i = 0; i < NS; ++i) mcur[i] = mnxt[i];
    }
  }

  auto VSTEP = [&](float em) {
    float f = __expf(em);
    float a0 = 0.f, a1 = 0.f, a2 = 0.f, a3 = 0.f;
#pragma unroll
    for (int i = 0; i < NS; i += 4) {
      a0 = fmaf(rdlane(alpha, i + 0), e[i + 0], a0);
      a1 = fmaf(rdlane(alpha, i + 1), e[i + 1], a1);
      a2 = fmaf(rdlane(alpha, i + 2), e[i + 2], a2);
      a3 = fmaf(rdlane(alpha, i + 3), e[i + 3], a3);
    }
    float qn = ((a0 + a1) + (a2 + a3)) * f;
    unsigned long long up = __ballot(qn >= 0x1p64f);
    unsigned long long dn = __ballot(qn >= 0x1p-64f);
    float s = up ? 0x1p-64f : (dn ? 1.0f : 0x1p64f);
    cnt32 += up ? 2 : (dn ? 0 : -2);
    alpha = qn * s;
  };

  {
    const float* p = base + (size_t)(CT * K + 1) * LL + cl;  // rows <=968 valid
    float ebuf[8];
#pragma unroll
    for (int kk = 0; kk < 8; ++kk) ebuf[kk] = p[(size_t)kk * LL];
    int u = 0;
    for (; u + 8 <= r; u += 8) {
#pragma unroll
      for (int s8 = 0; s8 < 8; ++s8) {
        VSTEP(ebuf[s8]);
        int tn = u + s8 + 8;
        tn = (tn < r) ? tn : 0;  // clamp: unused slots read a valid row
        ebuf[s8] = p[(size_t)tn * LL];
      }
    }
    if (u + 0 < r) VSTEP(ebuf[0]);
    if (u + 1 < r) VSTEP(ebuf[1]);
    if (u + 2 < r) VSTEP(ebuf[2]);
    if (u + 3 < r) VSTEP(ebuf[3]);
    if (u + 4 < r) VSTEP(ebuf[4]);
    if (u + 5 < r) VSTEP(ebuf[5]);
    if (u + 6 < r) VSTEP(ebuf[6]);
  }

  float w = 0.0f;
  if (act) w = alpha * __expf(trans[lane * LL + END_I]);
#pragma unroll
  for (int off = 32; off > 0; off >>= 1) w += __shfl_xor(w, off, 64);
  float unl = (float)cnt32 * 22.180709777918249f + __logf(w);

  const int* tg = tags + (size_t)b * TT;
  float lab = 0.0f;
  for (int t0 = 0; t0 < len; t0 += 64) {
    int t = t0 + lane;
    if (t >= 1 && t < len) {
      int tp = tg[t - 1];
      int tc = tg[t];
      lab += trans[tp * LL + tc] + lstm[((size_t)b * TT + t) * LL + tc];
    }
  }
#pragma unroll
  for (int off = 32; off > 0; off >>= 1) lab += __shfl_xor(lab, off, 64);

  if (lane == 0) {
    int tg0 = tg[0];
    float begin = trans[START_I * LL + tg0] + lstm[(size_t)b * TT * LL + tg0];
    int tgl = tg[len - 1];
    float endv = trans[tgl * LL + END_I];
    wsf[b] = unl;
    wsf[BB + b] = lab + begin + endv;
  }
}

// ============================================================================
// Legacy fallback: round-3 kernel (proven, absmax 0), if ws too small.
// ============================================================================
__global__ __launch_bounds__(64) __attribute__((amdgpu_waves_per_eu(1, 1)))
void crf_fwd_legacy(
    const float* __restrict__ lstm, const float* __restrict__ trans,
    const int* __restrict__ lens, const int* __restrict__ tags,
    float* __restrict__ ws) {
  const int b = blockIdx.x;
  const int lane = threadIdx.x;
  const bool act = lane < LL;
  const int cl = act ? lane : (LL - 1);
  const int len = lens[b];

  float e[LL];
#pragma unroll
  for (int i = 0; i < LL; ++i) {
    float ev = __expf(trans[i * LL + cl]);
    e[i] = act ? ev : 0.0f;
  }
  const float* __restrict__ base = lstm + (size_t)b * TT * LL + cl;
  float q = act ? __expf(trans[START_I * LL + lane] + base[0]) : 0.0f;
  int cnt = 0;
  float s_pend = 1.0f;

  auto STEP = [&](float em) {
    float f = __expf(em) * s_pend;
    float acc0 = 0.f, acc1 = 0.f, acc2 = 0.f, acc3 = 0.f;
#pragma unroll
    for (int i = 0; i < 48; i += 4) {
      acc0 = fmaf(rdlane(q, i + 0), e[i + 0], acc0);
      acc1 = fmaf(rdlane(q, i + 1), e[i + 1], acc1);
      acc2 = fmaf(rdlane(q, i + 2), e[i + 2], acc2);
      acc3 = fmaf(rdlane(q, i + 3), e[i + 3], acc3);
    }
    acc0 = fmaf(rdlane(q, 48), e[48], acc0);
    acc1 = fmaf(rdlane(q, 49), e[49], acc1);
    float qn = ((acc0 + acc1) + (acc2 + acc3)) * f;
    unsigned long long up = __ballot(qn >= 0x1p64f);
    unsigned long long dn = __ballot(qn >= 0x1p-64f);
    s_pend = up ? 0x1p-64f : (dn ? 1.0f : 0x1p64f);
    cnt += up ? 1 : (dn ? 0 : -1);
    q = qn;
  };

  float ebuf[8];
  const float* p = base + LL;
#pragma unroll
  for (int k = 0; k < 8; ++k) ebuf[k] = p[k * LL];
  const int nb = (len - 1) >> 3;
  const int rem = (len - 1) & 7;
  for (int blk = 0; blk < nb; ++blk) {
    const float* pf = p + 8 * LL;
    if (blk < 126) {
#pragma unroll
      for (int u = 0; u < 8; ++u) {
        STEP(ebuf[u]);
        ebuf[u] = pf[u * LL];
      }
    } else {
#pragma unroll
      for (int u = 0; u < 8; ++u) {
        STEP(ebuf[u]);
        int tn = 9 + 8 * blk + u;
        if (tn < TT) ebuf[u] = pf[u * LL];
      }
    }
    p = pf;
  }
  for (int u = 0; u < rem; ++u) STEP(ebuf[u]);
  q *= s_pend;

  float wv = 0.0f;
  if (act) wv = q * __expf(trans[lane * LL + END_I]);
#pragma unroll
  for (int off = 32; off > 0; off >>= 1) wv += __shfl_xor(wv, off, 64);
  float unl = (float)cnt * 44.361419555836498f + __logf(wv);

  const int* tg = tags + (size_t)b * TT;
  float lab = 0.0f;
  for (int t0 = 0; t0 < len; t0 += 64) {
    int t = t0 + lane;
    if (t >= 1 && t < len) {
      int tp = tg[t - 1];
      int tc = tg[t];
      lab += trans[tp * LL + tc] + lstm[((size_t)b * TT + t) * LL + tc];
    }
  }
#pragma unroll
  for (int off = 32; off > 0; off >>= 1) lab += __shfl_xor(lab, off, 64);

  if (lane == 0) {
    int tg0 = tg[0];
    float begin = trans[START_I * LL + tg0] + lstm[(size_t)b * TT * LL + tg0];
    int tgl = tg[len - 1];
    float endv = trans[tgl * LL + END_I];
    ws[b] = unl;
    ws[BB + b] = lab + begin + endv;
  }
}

// Deterministic final reduce: ws[0..255] -> out[0], ws[256..511] -> out[1]
__global__ __launch_bounds__(256) void crf_reduce(const float* __restrict__ ws,
                                                  float* __restrict__ out) {
  __shared__ float sm[8];
  int tid = threadIdx.x;
  float u = ws[tid];
  float l = ws[BB + tid];
#pragma unroll
  for (int off = 32; off > 0; off >>= 1) {
    u += __shfl_xor(u, off, 64);
    l += __shfl_xor(l, off, 64);
  }
  int wid = tid >> 6;
  if ((tid & 63) == 0) {
    sm[wid] = u;
    sm[4 + wid] = l;
  }
  __syncthreads();
  if (tid == 0) {
    out[0] = (sm[0] + sm[1]) + (sm[2] + sm[3]);
    out[1] = (sm[4] + sm[5]) + (sm[6] + sm[7]);
  }
}

extern "C" void kernel_launch(void* const* d_in, const int* in_sizes, int n_in,
                              void* d_out, int out_size, void* d_ws, size_t ws_size,
                              hipStream_t stream) {
  const float* lstm = (const float*)d_in[0];
  const float* trans = (const float*)d_in[1];
  const int* lens = (const int*)d_in[2];
  const int* tags = (const int*)d_in[3];
  float* out = (float*)d_out;

  const size_t fexpN = (size_t)BB * TT * 24;       // uints (25.2 MB)
  const size_t MbN = (size_t)BB * NCH * MSTRIDE;   // floats (35.4 MB)
  size_t need = fexpN * 4 + MbN * 4 + (size_t)BB * NCH * 4 + (size_t)BB * 2 * 4;
  if (ws_size >= need) {
    unsigned* fexp = (unsigned*)d_ws;
    float* Mb = (float*)(fexp + fexpN);
    int* Mc = (int*)(Mb + MbN);
    float* wsf = (float*)(Mc + BB * NCH);
    crf_prep_exp<<<dim3(BB * TT * 24 / 256), dim3(256), 0, stream>>>(lstm, fexp);
    crf_pass1<<<dim3(BB * NCH), dim3(64), 0, stream>>>(fexp, trans, Mb, Mc);
    crf_pass2<<<dim3(BB), dim3(64), 0, stream>>>(lstm, trans, lens, tags, Mb, Mc,
                                                 wsf);
    crf_reduce<<<dim3(1), dim3(256), 0, stream>>>(wsf, out);
  } else {
    float* wsf = (float*)d_ws;
    crf_fwd_legacy<<<dim3(BB), dim3(64), 0, stream>>>(lstm, trans, lens, tags, wsf);
    crf_reduce<<<dim3(1), dim3(256), 0, stream>>>(wsf, out);
  }
}